// Round 7
// baseline (92.292 us; speedup 1.0000x reference)
//
#include <hip/hip_runtime.h>

#define TID threadIdx.x

constexpr int B = 2, C = 256, N = 2048, H = 8, D = 32, BH = 16;
constexpr float EPS = 1e-5f;
constexpr float SCL2 = 0.25505654344454694f; // 32^-0.5 * log2(e)
constexpr size_t SZ = (size_t)BH * N * D;    // 1048576 elements per Q/K/V buffer

typedef _Float16 h8 __attribute__((ext_vector_type(8)));
typedef _Float16 h4 __attribute__((ext_vector_type(4)));
typedef float f32x4 __attribute__((ext_vector_type(4)));

// ---------------- kernel 1: batchnorm stats (mean, rstd per channel) ----------------
__global__ __launch_bounds__(256) void k_bnstats(const float* __restrict__ x,
                                                 float* __restrict__ stats) {
  int c = blockIdx.x;
  float s = 0.f, ss = 0.f;
  const float4* x4 = (const float4*)x;
  for (int k = 0; k < B; ++k) {
    const float4* p = x4 + (size_t)(k * C + c) * (N / 4);
    for (int i = TID; i < N / 4; i += 256) {
      float4 v = p[i];
      s += v.x + v.y + v.z + v.w;
      ss += v.x * v.x + v.y * v.y + v.z * v.z + v.w * v.w;
    }
  }
#pragma unroll
  for (int off = 32; off; off >>= 1) {
    s += __shfl_down(s, off);
    ss += __shfl_down(ss, off);
  }
  __shared__ float red[8];
  int w = TID >> 6;
  if ((TID & 63) == 0) { red[w] = s; red[4 + w] = ss; }
  __syncthreads();
  if (TID == 0) {
    float S = red[0] + red[1] + red[2] + red[3];
    float SS = red[4] + red[5] + red[6] + red[7];
    float mean = S * (1.f / (B * N));
    float var = SS * (1.f / (B * N)) - mean * mean;
    stats[c] = mean;
    stats[C + c] = rsqrtf(var + EPS);
  }
}

// ---------------- kernel 2: fused BN-apply + grouped conv projections (fp16 out) --------
// All of Qa/Ka/Va: fp16 [bh][n][d] (coalesced). Channel-split quirk + q/k swap applied.
__global__ __launch_bounds__(256) void k_proj(const float* __restrict__ x,
    const float* __restrict__ gamma, const float* __restrict__ beta,
    const float* __restrict__ wk, const float* __restrict__ wq,
    const float* __restrict__ wv, const float* __restrict__ stats,
    _Float16* __restrict__ qa, _Float16* __restrict__ ka, _Float16* __restrict__ va) {
  int proj = blockIdx.x >> 8;
  int rem = blockIdx.x & 255;
  int b = rem >> 7;
  int n0 = (rem & 127) * 16;
  const float* w = proj == 0 ? wk : (proj == 1 ? wq : wv);
  _Float16* out = proj == 0 ? qa : (proj == 1 ? ka : va);

  __shared__ float w_s[256 * 33];  // row (d + 32h) holds w[8d+h][*]
  __shared__ float xs[256 * 20];   // row (g + 8c) holds xn channel g*32+c

#pragma unroll
  for (int p = 0; p < 32; ++p) {
    int ch = p * 8 + (TID >> 5);
    int cc = TID & 31;
    float wval = w[ch * 32 + cc];
    int row = (ch >> 3) + ((ch & 7) << 5);  // d + 32h
    w_s[row * 33 + cc] = wval;
  }
#pragma unroll
  for (int p = 0; p < 16; ++p) {
    int cc = p * 16 + (TID >> 4);
    int nl = TID & 15;
    float v = x[(size_t)(b * C + cc) * N + n0 + nl];
    float a = stats[C + cc] * gamma[cc];
    float xn = (v - stats[cc]) * a + beta[cc];
    int row = (cc >> 5) + ((cc & 31) << 3);  // g + 8c
    xs[row * 20 + nl] = xn;
  }
  __syncthreads();

  int d = TID & 31;
  int t2 = TID >> 5;  // n = n0 + t2*2 + {0,1}
#pragma unroll
  for (int h = 0; h < 8; ++h) {
    int g = (d * 8 + h) >> 5;
    const float* wrow = &w_s[(d + h * 32) * 33];
    float2 acc = {0.f, 0.f};
#pragma unroll
    for (int c = 0; c < 32; ++c) {
      float wv2 = wrow[c];
      float2 xv = *(const float2*)&xs[(g + c * 8) * 20 + t2 * 2];
      acc.x += wv2 * xv.x;
      acc.y += wv2 * xv.y;
    }
    int n = n0 + t2 * 2;
    size_t bh = (size_t)(b * 8 + h);
    size_t o = (bh * N + n) * D + d;
    out[o] = (_Float16)acc.x;
    out[o + D] = (_Float16)acc.y;
  }
}

// ---------------- kernel 3: MFMA fp16 flash attention (JS=2, exp2 domain) ----------------
// Block = 4 waves x 16 q-rows = 64 rows. grid = 1024: XCD-swizzled (js,bh,rb).
// Writes UNNORMALIZED partials op[js][b][h*32+d][n] + m/l (log2 domain).
__global__ __launch_bounds__(256, 4) void k_attn(
    const _Float16* __restrict__ qa, const _Float16* __restrict__ ka,
    const _Float16* __restrict__ va, float* __restrict__ op,
    float* __restrict__ mp, float* __restrict__ lp) {
  int bid = blockIdx.x;
  int r = bid & 7;          // XCD id (round-robin dispatch)
  int q = bid >> 3;         // 0..127
  int js = q >> 6;
  int bh = r * 2 + ((q >> 5) & 1);
  int rb = q & 31;
  constexpr int ntiles = 16;  // 1024 j's per js half

  int w = TID >> 6;
  int lane = TID & 63;
  int il = lane & 15;
  int g = lane >> 4;

  __shared__ char Kc[4096];      // K tile [64 j][32 d] fp16, rows 64B, swz ^((j&3)<<4)
  __shared__ char Vc[4096];      // V^T tile [32 d][64 j] fp16, rows 128B, swz f(d)
  __shared__ char Pc[4 * 2048];  // per-wave P^T [16 i][64 j] fp16, swz ^((i&7)<<4)
  char* Pw = Pc + w * 2048;

  int n_q = rb * 64 + w * 16 + il;
  h8 qf = *(const h8*)(qa + ((size_t)bh * N + n_q) * D + g * 8);

  f32x4 accO[2];
#pragma unroll
  for (int dh = 0; dh < 2; ++dh) accO[dh] = (f32x4){0.f, 0.f, 0.f, 0.f};
  float m = -3.0e38f, l = 0.f;

  int kj = TID >> 2, kc = TID & 3;
  const _Float16* kbase = ka + ((size_t)bh * N + (size_t)js * 1024 + kj) * D + kc * 8;
  const _Float16* vbase = va + ((size_t)bh * N + (size_t)js * 1024 + kj) * D + kc * 8;
  int kdst = (kj * 64 + kc * 16) ^ ((kj & 3) << 4);

  h8 kreg = *(const h8*)kbase;
  h8 vreg = *(const h8*)vbase;

  for (int t = 0; t < ntiles; ++t) {
    __syncthreads();
    *(h8*)(Kc + kdst) = kreg;
#pragma unroll
    for (int e = 0; e < 8; ++e) {  // V transpose-scatter
      int d = kc * 8 + e;
      int addr = (d * 128 + kj * 2) ^ ((d & 7) << 4) ^ (((d >> 3) & 3) << 5);
      *(_Float16*)(Vc + addr) = vreg[e];
    }
    if (t + 1 < ntiles) {
      kreg = *(const h8*)(kbase + (size_t)(t + 1) * 64 * D);
      vreg = *(const h8*)(vbase + (size_t)(t + 1) * 64 * D);
    }
    __syncthreads();

    // ---- QK^T -> scores in log2 domain ----
    float pv[4][4];
    float tmax = -3.0e38f;
#pragma unroll
    for (int jt = 0; jt < 4; ++jt) {
      int krow = jt * 16 + il;
      h8 kf = *(const h8*)(Kc + ((krow * 64 + g * 16) ^ ((krow & 3) << 4)));
      f32x4 accS = (f32x4){0.f, 0.f, 0.f, 0.f};
      accS = __builtin_amdgcn_mfma_f32_16x16x32_f16(kf, qf, accS, 0, 0, 0);
#pragma unroll
      for (int e = 0; e < 4; ++e) {
        float xv = accS[e] * SCL2;
        pv[jt][e] = xv;
        tmax = fmaxf(tmax, xv);
      }
    }
    tmax = fmaxf(tmax, __shfl_xor(tmax, 16));
    tmax = fmaxf(tmax, __shfl_xor(tmax, 32));
    float mn = fmaxf(m, tmax);
    float corr = exp2f(m - mn);
    float ls = 0.f;
#pragma unroll
    for (int jt = 0; jt < 4; ++jt)
#pragma unroll
      for (int e = 0; e < 4; ++e) {
        float pe = exp2f(pv[jt][e] - mn);
        pv[jt][e] = pe;
        ls += pe;
      }
    ls += __shfl_xor(ls, 16);
    ls += __shfl_xor(ls, 32);
    l = l * corr + ls;
    m = mn;
#pragma unroll
    for (int dh = 0; dh < 2; ++dh)
#pragma unroll
      for (int e = 0; e < 4; ++e) accO[dh][e] *= corr;

    // ---- P -> wave-private LDS ----
#pragma unroll
    for (int jt = 0; jt < 4; ++jt) {
      h4 ph = {(_Float16)pv[jt][0], (_Float16)pv[jt][1],
               (_Float16)pv[jt][2], (_Float16)pv[jt][3]};
      *(h4*)(Pw + ((il * 128 + jt * 32 + g * 8) ^ ((il & 7) << 4))) = ph;
    }

    // ---- PV ----
#pragma unroll
    for (int jb = 0; jb < 2; ++jb) {
      h8 pf = *(const h8*)(Pw + ((il * 128 + jb * 64 + g * 16) ^ ((il & 7) << 4)));
#pragma unroll
      for (int dh = 0; dh < 2; ++dh) {
        int vrow = dh * 16 + il;
        int vaddr = (vrow * 128 + jb * 64 + g * 16) ^ ((vrow & 7) << 4) ^
                    (((vrow >> 3) & 3) << 5);
        h8 vf = *(const h8*)(Vc + vaddr);
        accO[dh] = __builtin_amdgcn_mfma_f32_16x16x32_f16(vf, pf, accO[dh], 0, 0, 0);
      }
    }
  }

  // epilogue: lane holds O^T[d=dh*16+g*4+e][i=il]; write op[js][b][h*32+d][n_q]
  int b = bh >> 3, h = bh & 7;
#pragma unroll
  for (int dh = 0; dh < 2; ++dh)
#pragma unroll
    for (int e = 0; e < 4; ++e) {
      int d = dh * 16 + g * 4 + e;
      op[((size_t)((js * 2 + b) * C) + h * 32 + d) * N + n_q] = accO[dh][e];
    }
  if (g == 0) {
    size_t idx = (size_t)(js * BH + bh) * N + n_q;
    mp[idx] = m;
    lp[idx] = l;
  }
}

// ---------------- kernel 4: fused combine + output 1x1 conv ----------------
// out[b,o,n] = sum_c wo[o,c] * (cw0[h,n]*op0[b,c,n] + cw1[h,n]*op1[b,c,n]) + bo[o]
__global__ __launch_bounds__(256) void k_final(const float* __restrict__ op,
    const float* __restrict__ mp, const float* __restrict__ lp,
    const float* __restrict__ wo, const float* __restrict__ bo,
    float* __restrict__ out) {
  __shared__ float w_s[256 * 33];   // [c][o_local] transposed, padded
  __shared__ float a_s[256 * 33];   // [c][n_local] combined attention tile
  __shared__ float cwa[8 * 32], cwb[8 * 32];
  int nt = blockIdx.x & 63, oq = (blockIdx.x >> 6) & 7, b = blockIdx.x >> 9;
  int n0 = nt * 32, o0 = oq * 32;

  // combine weights per (h, n_local): all in log2 domain
  {
    int h = TID >> 5, n_l = TID & 31;
    size_t i0 = (size_t)(b * 8 + h) * N + n0 + n_l;
    size_t i1 = (size_t)(BH + b * 8 + h) * N + n0 + n_l;
    float m0 = mp[i0], m1 = mp[i1];
    float mg = fmaxf(m0, m1);
    float w0 = exp2f(m0 - mg), w1 = exp2f(m1 - mg);
    float inv = 1.f / (w0 * lp[i0] + w1 * lp[i1]);
    cwa[TID] = w0 * inv;
    cwb[TID] = w1 * inv;
  }
  // weight tile: wo[(o0+o_l)*256 + c] -> w_s[c][o_l]
#pragma unroll
  for (int p = 0; p < 8; ++p) {
    int idx = p * 256 + TID;
    int o_l = idx >> 6, c4 = idx & 63;
    float4 wv = ((const float4*)wo)[(o0 + o_l) * 64 + c4];
    w_s[(c4 * 4 + 0) * 33 + o_l] = wv.x;
    w_s[(c4 * 4 + 1) * 33 + o_l] = wv.y;
    w_s[(c4 * 4 + 2) * 33 + o_l] = wv.z;
    w_s[(c4 * 4 + 3) * 33 + o_l] = wv.w;
  }
  __syncthreads();  // cwa/cwb ready before a_s staging uses them
  // combined attention tile: a_s[c][n_l] = cw0*op0 + cw1*op1
#pragma unroll
  for (int p = 0; p < 8; ++p) {
    int idx = p * 256 + TID;
    int c = idx >> 3, n4 = idx & 7;
    int h = c >> 5;
    size_t base0 = ((size_t)(b * C + c)) * N + n0 + n4 * 4;
    size_t base1 = ((size_t)((2 + b) * C + c)) * N + n0 + n4 * 4;
    float4 v0 = *(const float4*)(op + base0);
    float4 v1 = *(const float4*)(op + base1);
    const float* ca = &cwa[h * 32 + n4 * 4];
    const float* cb = &cwb[h * 32 + n4 * 4];
    a_s[c * 33 + n4 * 4 + 0] = ca[0] * v0.x + cb[0] * v1.x;
    a_s[c * 33 + n4 * 4 + 1] = ca[1] * v0.y + cb[1] * v1.y;
    a_s[c * 33 + n4 * 4 + 2] = ca[2] * v0.z + cb[2] * v1.z;
    a_s[c * 33 + n4 * 4 + 3] = ca[3] * v0.w + cb[3] * v1.w;
  }
  __syncthreads();

  int n_l = TID & 31, og = TID >> 5;
  float acc[4] = {0.f, 0.f, 0.f, 0.f};
  for (int c = 0; c < 256; ++c) {
    float4 w4 = *(const float4*)&w_s[c * 33 + og * 4];
    float av = a_s[c * 33 + n_l];
    acc[0] += w4.x * av;
    acc[1] += w4.y * av;
    acc[2] += w4.z * av;
    acc[3] += w4.w * av;
  }
#pragma unroll
  for (int k = 0; k < 4; ++k) {
    int o = o0 + og * 4 + k;
    out[(size_t)(b * C + o) * N + n0 + n_l] = acc[k] + bo[o];
  }
}

extern "C" void kernel_launch(void* const* d_in, const int* in_sizes, int n_in,
                              void* d_out, int out_size, void* d_ws, size_t ws_size,
                              hipStream_t stream) {
  const float* x = (const float*)d_in[0];
  const float* gamma = (const float*)d_in[1];
  const float* beta = (const float*)d_in[2];
  const float* wk = (const float*)d_in[3];
  const float* wq = (const float*)d_in[4];
  const float* wv = (const float*)d_in[5];
  const float* wo = (const float*)d_in[6];
  const float* bo = (const float*)d_in[7];
  float* out = (float*)d_out;
  float* ws = (float*)d_ws;

  float* stats = ws;
  _Float16* qa = (_Float16*)(ws + 1024);
  _Float16* ka = qa + SZ;
  _Float16* va = ka + SZ;
  float* op = (float*)(va + SZ);          // [js][b][C][N] fp32, 2*SZ floats
  float* mp = op + 2 * SZ;                // [js*BH + bh][N]
  float* lp = mp + 2 * (size_t)BH * N;

  k_bnstats<<<256, 256, 0, stream>>>(x, stats);
  k_proj<<<768, 256, 0, stream>>>(x, gamma, beta, wk, wq, wv, stats, qa, ka, va);
  k_attn<<<1024, 256, 0, stream>>>(qa, ka, va, op, mp, lp);
  k_final<<<1024, 256, 0, stream>>>(op, mp, lp, wo, bo, out);
}